// Round 9
// baseline (516.269 us; speedup 1.0000x reference)
//
#include <hip/hip_runtime.h>
#include <math.h>

#define B_ 8
#define L_ 2048
#define DM 6
#define ED 48
#define NS 32
#define DCONV 16
#define NLAYERS 4
#define NCLASSES 4
#define EPS 1e-5f

#define CH 64              // chunks per sequence
#define CL 32              // steps per chunk (== fused tile width)
#define HALO (DCONV - 1)   // 15
#define TP (CL + HALO)     // 47 positions incl. halo

// Layouts:
//   z, xc, delta, y : [b][e][l]   (l contiguous)
//   Bm, Cm          : [b][l][n]   (n contiguous)
//   gA, gH          : [b*ED+e][chunk][n]  chunk summaries

// ---------------------------------------------------------------------------
// Fused pre-scan + local-chunk-scan kernel. Block = (b, 32-pos chunk).
__global__ void __launch_bounds__(256) k_fused_pre(
    const float* __restrict__ x,      // [b][l][dm] raw input (layer 0)
    const float* __restrict__ yprev,  // [b][e][l] gated y of prev layer
    const float* __restrict__ outw,   // (6,48) prev layer out_proj
    const float* __restrict__ hin,    // [b][dm][l] residual in (layer>0)
    float* __restrict__ hout,         // [b][dm][l] residual out (layer<3)
    const float* __restrict__ ipw,    // (96,6)
    const float* __restrict__ nw,     // (6)
    const float* __restrict__ cw,     // (48,16)
    const float* __restrict__ cb,     // (48)
    const float* __restrict__ xpw,    // (65,48)
    const float* __restrict__ dtw,    // (48)
    const float* __restrict__ dtb,    // (48)
    const float* __restrict__ A_log,  // (48,32)
    float* __restrict__ z,
    float* __restrict__ xcg,
    float* __restrict__ delta,
    float* __restrict__ Bm, float* __restrict__ Cm,
    float* __restrict__ gA, float* __restrict__ gH,
    int layer)
{
    __shared__ float sh[DM][TP + 1];
    __shared__ float srn[TP + 1];
    __shared__ float sxin[ED][TP + 1];
    __shared__ float sxc[ED][CL + 1];
    __shared__ float sdel[ED][CL];
    __shared__ float sB[CL][NS + 1];
    __shared__ float sdr[CL];

    int b     = blockIdx.x >> 6;         // 64 chunks per batch
    int chunk = blockIdx.x & (CH - 1);
    int l0    = chunk * CL;
    int tid   = threadIdx.x;

    // ---- A1: residual h for TP positions (halo recomputed) ----
    for (int i = tid; i < DM * TP; i += 256) {
        int d = i / TP, p = i - d * TP;
        int l = l0 - HALO + p;
        float hv = 0.f;
        if (l >= 0) {
            if (layer == 0) {
                hv = x[((size_t)b * L_ + l) * DM + d];
            } else {
                hv = hin[((size_t)b * DM + d) * L_ + l];
                const float* yp = yprev + (size_t)b * ED * L_ + l;
                const float* wp = outw + d * ED;
                float acc = 0.f;
#pragma unroll
                for (int e = 0; e < ED; ++e) acc += yp[(size_t)e * L_] * wp[e];
                hv += acc;
            }
            if (p >= HALO && layer < NLAYERS - 1)
                hout[((size_t)b * DM + d) * L_ + l] = hv;
        }
        sh[d][p] = hv;
    }
    __syncthreads();

    // ---- A2: rms scale ----
    if (tid < TP) {
        float ss = 0.f;
#pragma unroll
        for (int d = 0; d < DM; ++d) ss += sh[d][tid] * sh[d][tid];
        srn[tid] = rsqrtf(ss * (1.f / DM) + EPS);
    }
    __syncthreads();

    // ---- A3: in_proj -> xin (TP pos, LDS) and z (CL pos, global) ----
    for (int i = tid; i < ED * TP; i += 256) {
        int e = i / TP, p = i - e * TP;
        const float* wp = ipw + e * DM;
        float acc = 0.f;
#pragma unroll
        for (int d = 0; d < DM; ++d) acc += sh[d][p] * nw[d] * wp[d];
        sxin[e][p] = acc * srn[p];
    }
    for (int i = tid; i < ED * CL; i += 256) {
        int e = i >> 5, po = i & 31;
        int p = po + HALO;
        const float* wp = ipw + (ED + e) * DM;
        float acc = 0.f;
#pragma unroll
        for (int d = 0; d < DM; ++d) acc += sh[d][p] * nw[d] * wp[d];
        z[((size_t)b * ED + e) * L_ + l0 + po] = acc * srn[p];
    }
    __syncthreads();

    // ---- A4: conv + SiLU ----
    for (int i = tid; i < ED * CL; i += 256) {
        int e = i >> 5, po = i & 31;
        const float* wp = cw + e * DCONV;
        float acc = cb[e];
#pragma unroll
        for (int k = 0; k < DCONV; ++k) acc += sxin[e][po + k] * wp[k];
        float v = acc / (1.f + __expf(-acc));
        sxc[e][po] = v;
        xcg[((size_t)b * ED + e) * L_ + l0 + po] = v;
    }
    __syncthreads();

    // ---- A5: x_proj (65 rows) -> Bm/Cm global, sB LDS, sdr ----
    {
        int og = tid >> 5, li = tid & 31;
        int isB = og < 4;
        int nb = (og & 3) * 8;
        int rowBase = isB ? (1 + nb) : (1 + NS + nb);
        const float* wr = xpw + rowBase * ED;
        float a0=0,a1=0,a2=0,a3=0,a4=0,a5=0,a6=0,a7=0, dr=0;
#pragma unroll 4
        for (int e = 0; e < ED; ++e) {
            float xv = sxc[e][li];
            a0 += xv * wr[0*ED+e]; a1 += xv * wr[1*ED+e];
            a2 += xv * wr[2*ED+e]; a3 += xv * wr[3*ED+e];
            a4 += xv * wr[4*ED+e]; a5 += xv * wr[5*ED+e];
            a6 += xv * wr[6*ED+e]; a7 += xv * wr[7*ED+e];
            dr += xv * xpw[e];
        }
        float* outp = (isB ? Bm : Cm) + ((size_t)(b * L_ + l0 + li)) * NS + nb;
        ((float4*)outp)[0] = make_float4(a0, a1, a2, a3);
        ((float4*)outp)[1] = make_float4(a4, a5, a6, a7);
        if (isB) {
            float* dst = &sB[li][nb];
            dst[0]=a0; dst[1]=a1; dst[2]=a2; dst[3]=a3;
            dst[4]=a4; dst[5]=a5; dst[6]=a6; dst[7]=a7;
        }
        if (og == 0) sdr[li] = dr;
    }
    __syncthreads();

    // ---- A6: delta = softplus(dr*dtw + dtb) -> global + LDS ----
    for (int i = tid; i < ED * CL; i += 256) {
        int e = i >> 5, po = i & 31;
        float s = sdr[po] * dtw[e] + dtb[e];
        float dv = fmaxf(s, 0.f) + log1pf(__expf(-fabsf(s)));
        sdel[e][po] = dv;
        delta[((size_t)b * ED + e) * L_ + l0 + po] = dv;
    }
    __syncthreads();

    // ---- B: local chunk scan from LDS, 6 chains per thread ----
    {
        int g2 = tid >> 5;
        int n  = tid & 31;
        int e0 = g2 * 6;
        float Aj[6], hb[6], sd[6];
#pragma unroll
        for (int j = 0; j < 6; ++j) {
            Aj[j] = -__expf(A_log[(e0 + j) * NS + n]);
            hb[j] = 0.f; sd[j] = 0.f;
        }
        for (int l = 0; l < CL; ++l) {
            float bb = sB[l][n];
#pragma unroll
            for (int j = 0; j < 6; ++j) {
                float dv = sdel[e0 + j][l];
                float xv = sxc[e0 + j][l];
                hb[j] = __expf(dv * Aj[j]) * hb[j] + (dv * xv) * bb;
                sd[j] += dv;
            }
        }
#pragma unroll
        for (int j = 0; j < 6; ++j) {
            size_t idx = ((size_t)(b * ED + e0 + j) * CH + chunk) * NS + n;
            gA[idx] = __expf(Aj[j] * sd[j]);
            gH[idx] = hb[j];
        }
    }
}

// ---------------------------------------------------------------------------
// Scan pass 2. Block = (b, chunk): owns all 48 channels of one 32-step chunk.
// 8 groups x 6 channels/thread (6-way ILP). Stages d/x/z/B/C in LDS.
// Folds predecessor summaries, rescans, butterfly-reduces over n, gates,
// writes y. Last layer: only chunk CH-1 blocks run + fused classifier.
__global__ void __launch_bounds__(256) k_scan(
    const float* __restrict__ delta, const float* __restrict__ xc,
    const float* __restrict__ Bm, const float* __restrict__ Cm,
    const float* __restrict__ z,
    const float* __restrict__ A_log,  // (48,32)
    const float* __restrict__ Dp,     // (48)
    const float* __restrict__ gA, const float* __restrict__ gH,
    float* __restrict__ y,
    const float* __restrict__ fcw, const float* __restrict__ fcb,
    float* __restrict__ out,
    int lastLayer)
{
    __shared__ float sdel[ED][CL];   // e-major, rows 128B (float4-clean)
    __shared__ float sxc[ED][CL];
    __shared__ float sz[ED][CL];
    __shared__ float sB[CL][NS];     // l-major
    __shared__ float sC[CL][NS];
    __shared__ float sy[ED];

    int b     = blockIdx.x >> 6;
    int chunk = blockIdx.x & (CH - 1);
    if (lastLayer && chunk != CH - 1) return;
    int l0  = chunk * CL;
    int tid = threadIdx.x;

    // ---- stage chunk into LDS (coalesced float4) ----
    for (int i = tid; i < ED * 8; i += 256) {          // 384 float4 per tensor
        int e = i >> 3, q = i & 7;
        size_t gi = ((size_t)(b * ED + e) * L_ + l0) / 4 + q;
        ((float4*)sdel)[i] = ((const float4*)delta)[gi];
        ((float4*)sxc)[i]  = ((const float4*)xc)[gi];
        ((float4*)sz)[i]   = ((const float4*)z)[gi];
    }
    {
        size_t gb = ((size_t)b * L_ + l0) * NS / 4;    // 256 float4 each
        ((float4*)sB)[tid] = ((const float4*)Bm)[gb + tid];
        ((float4*)sC)[tid] = ((const float4*)Cm)[gb + tid];
    }
    __syncthreads();

    int grp = tid >> 5;
    int n   = tid & 31;
    int e0  = grp * 6;

    float Aj[6], h[6], Dv[6];
#pragma unroll
    for (int j = 0; j < 6; ++j) {
        Aj[j] = -__expf(A_log[(e0 + j) * NS + n]);
        Dv[j] = Dp[e0 + j];
        h[j]  = 0.f;
    }

    // ---- lookback fold: 6 independent chains, coalesced loads ----
    for (int c = 0; c < chunk; ++c) {
#pragma unroll
        for (int j = 0; j < 6; ++j) {
            size_t idx = ((size_t)(b * ED + e0 + j) * CH + c) * NS + n;
            h[j] = gA[idx] * h[j] + gH[idx];
        }
    }

    int s0 = n & 1, s1 = n & 2;
    const float4* sdel4 = (const float4*)sdel;
    const float4* sxc4  = (const float4*)sxc;

    for (int q = 0; q < CL / 4; ++q) {
        float bb0 = sB[4*q+0][n], bb1 = sB[4*q+1][n];
        float bb2 = sB[4*q+2][n], bb3 = sB[4*q+3][n];
        float cc0 = sC[4*q+0][n], cc1 = sC[4*q+1][n];
        float cc2 = sC[4*q+2][n], cc3 = sC[4*q+3][n];
        float p[6][4];
        float4 xs[6];
#pragma unroll
        for (int j = 0; j < 6; ++j) {
            float4 d4 = sdel4[(e0 + j) * 8 + q];
            float4 x4 = sxc4[(e0 + j) * 8 + q];
            xs[j] = x4;
            float hj = h[j], A = Aj[j];
            hj = __expf(d4.x*A)*hj + (d4.x*x4.x)*bb0;  p[j][0] = hj*cc0;
            hj = __expf(d4.y*A)*hj + (d4.y*x4.y)*bb1;  p[j][1] = hj*cc1;
            hj = __expf(d4.z*A)*hj + (d4.z*x4.z)*bb2;  p[j][2] = hj*cc2;
            hj = __expf(d4.w*A)*hj + (d4.w*x4.w)*bb3;  p[j][3] = hj*cc3;
            h[j] = hj;
        }
#pragma unroll
        for (int j = 0; j < 6; ++j) {
            float u  = s0 ? p[j][1] : p[j][0];
            float us = s0 ? p[j][0] : p[j][1];
            u += __shfl_xor(us, 1, 32);
            float v  = s0 ? p[j][3] : p[j][2];
            float vs = s0 ? p[j][2] : p[j][3];
            v += __shfl_xor(vs, 1, 32);
            float wv  = s1 ? v : u;
            float wvs = s1 ? u : v;
            wv += __shfl_xor(wvs, 2, 32);
            wv += __shfl_xor(wv, 4, 32);
            wv += __shfl_xor(wv, 8, 32);
            wv += __shfl_xor(wv, 16, 32);
            if (n < 4) {
                float xv = (n == 0) ? xs[j].x : (n == 1) ? xs[j].y
                         : (n == 2) ? xs[j].z : xs[j].w;
                float yr = wv + Dv[j] * xv;
                float zv = sz[e0 + j][4*q + n];
                float yo = yr * (zv / (1.f + __expf(-zv)));
                y[((size_t)(b * ED + e0 + j)) * L_ + l0 + 4*q + n] = yo;
                if (lastLayer && q == CL/4 - 1 && n == 3) sy[e0 + j] = yo;
            }
        }
    }

    // ---- fused classifier (last layer, chunk CH-1 only) ----
    if (lastLayer) {
        __syncthreads();
        if (tid < NCLASSES) {
            float acc = fcb[tid];
#pragma unroll
            for (int e = 0; e < ED; ++e) acc += sy[e] * fcw[tid * ED + e];
            out[b * NCLASSES + tid] = acc;
        }
    }
}

// ---------------------------------------------------------------------------
extern "C" void kernel_launch(void* const* d_in, const int* in_sizes, int n_in,
                              void* d_out, int out_size, void* d_ws, size_t ws_size,
                              hipStream_t stream)
{
    const float* x          = (const float*)d_in[0];
    const float* in_proj_w  = (const float*)d_in[1];
    const float* conv_w     = (const float*)d_in[2];
    const float* conv_b     = (const float*)d_in[3];
    const float* x_proj_w   = (const float*)d_in[4];
    const float* dt_proj_w  = (const float*)d_in[5];
    const float* dt_proj_b  = (const float*)d_in[6];
    const float* A_log      = (const float*)d_in[7];
    const float* Dp         = (const float*)d_in[8];
    const float* out_proj_w = (const float*)d_in[9];
    const float* norm_w     = (const float*)d_in[10];
    const float* fc_w       = (const float*)d_in[11];
    const float* fc_b       = (const float*)d_in[12];

    float* ws    = (float*)d_ws;
    float* z     = ws;                          // B*48*L = 786432
    float* xc    = z     + (size_t)B_ * ED * L_;
    float* delta = xc    + (size_t)B_ * ED * L_;
    float* y     = delta + (size_t)B_ * ED * L_;
    float* Bmat  = y     + (size_t)B_ * ED * L_;   // B*L*32 = 524288
    float* Cmat  = Bmat  + (size_t)B_ * L_ * NS;
    float* hA    = Cmat  + (size_t)B_ * L_ * NS;   // B*6*L = 98304
    float* hB    = hA    + (size_t)B_ * DM * L_;
    float* gA    = hB    + (size_t)B_ * DM * L_;   // B*ED*CH*NS = 786432
    float* gH    = gA    + (size_t)B_ * ED * CH * NS;

    for (int i = 0; i < NLAYERS; ++i) {
        float* hout      = (i & 1) ? hB : hA;
        const float* hin = (i & 1) ? hA : hB;
        const float* ow  = (i == 0) ? out_proj_w
                                    : out_proj_w + (size_t)(i - 1) * DM * ED;
        k_fused_pre<<<B_ * CH, 256, 0, stream>>>(
            x, y, ow, hin, hout,
            in_proj_w + (size_t)i * 96 * DM, norm_w + (size_t)i * DM,
            conv_w + (size_t)i * ED * DCONV, conv_b + (size_t)i * ED,
            x_proj_w + (size_t)i * 65 * ED,
            dt_proj_w + (size_t)i * ED, dt_proj_b + (size_t)i * ED,
            A_log + (size_t)i * ED * NS,
            z, xc, delta, Bmat, Cmat, gA, gH, i);
        k_scan<<<B_ * CH, 256, 0, stream>>>(
            delta, xc, Bmat, Cmat, z,
            A_log + (size_t)i * ED * NS, Dp + (size_t)i * ED,
            gA, gH, y, fc_w, fc_b, (float*)d_out,
            (i == NLAYERS - 1) ? 1 : 0);
    }
}